// Round 3
// baseline (437.495 us; speedup 1.0000x reference)
//
#include <hip/hip_runtime.h>
#include <hip/hip_bf16.h>
#include <stdint.h>

#define Bsz 2
#define NT  2048
#define DM  768
#define NH  12
#define HD  64
#define MT  (Bsz * NT)   // 4096 tokens total

typedef float  f32x4  __attribute__((ext_vector_type(4)));
typedef short  s16x8  __attribute__((ext_vector_type(8)));
typedef __bf16 bf16x8 __attribute__((ext_vector_type(8)));

__device__ inline unsigned short f2bf(float f) {
    union { float f; uint32_t u; } v; v.f = f;
    uint32_t u = v.u;
    return (unsigned short)((u + 0x7FFFu + ((u >> 16) & 1u)) >> 16);  // RNE
}
__device__ inline float bf2f(unsigned short h) {
    union { uint32_t u; float f; } v; v.u = ((uint32_t)h) << 16;
    return v.f;
}
__device__ inline bf16x8 ldb(const short* p) {
    return __builtin_bit_cast(bf16x8, *(const s16x8*)p);
}

// ---------------- conversion kernels ----------------

__global__ __launch_bounds__(256) void cvt_x_kernel(const float* __restrict__ x,
                                                    short* __restrict__ xh,
                                                    short* __restrict__ xl, int n8) {
    int i = blockIdx.x * blockDim.x + threadIdx.x;
    if (i >= n8) return;
    const float4* p = (const float4*)x + (size_t)i * 2;
    float4 a = p[0], b = p[1];
    float v[8] = {a.x, a.y, a.z, a.w, b.x, b.y, b.z, b.w};
    union { unsigned short s[8]; uint4 q; } H, L;
#pragma unroll
    for (int j = 0; j < 8; ++j) {
        unsigned short h = f2bf(v[j]);
        H.s[j] = h;
        L.s[j] = f2bf(v[j] - bf2f(h));   // residual: x ~= hi + lo to ~17 mantissa bits
    }
    ((uint4*)xh)[i] = H.q;
    ((uint4*)xl)[i] = L.q;
}

__global__ __launch_bounds__(256) void cvt_w_kernel(const float* __restrict__ Wq,
                                                    const float* __restrict__ Wk,
                                                    const float* __restrict__ Wv,
                                                    short* __restrict__ Wh,
                                                    short* __restrict__ Wl, int per8) {
    int i = blockIdx.x * blockDim.x + threadIdx.x;
    if (i >= 3 * per8) return;
    const float* src; int j;
    if (i < per8)          { src = Wq; j = i; }
    else if (i < 2 * per8) { src = Wk; j = i - per8; }
    else                   { src = Wv; j = i - 2 * per8; }
    const float4* p = (const float4*)src + (size_t)j * 2;
    float4 a = p[0], b = p[1];
    float v[8] = {a.x, a.y, a.z, a.w, b.x, b.y, b.z, b.w};
    union { unsigned short s[8]; uint4 q; } H, L;
#pragma unroll
    for (int t = 0; t < 8; ++t) {
        unsigned short h = f2bf(v[t]);
        H.s[t] = h;
        L.s[t] = f2bf(v[t] - bf2f(h));
    }
    ((uint4*)Wh)[i] = H.q;
    ((uint4*)Wl)[i] = L.q;
}

// ---------------- QKV projection: y = x @ W^T (hi/lo x, hi/lo W) ----------------
// y = xh*Wh + xl*Wh + xh*Wl (dropped xl*Wl ~ 2^-18 rel). Q,K stored as hi/lo bf16
// pairs so QK^T can reconstruct ~17-bit logits; V stored single bf16, transposed.

__global__ __launch_bounds__(256) void qkv_proj_kernel(const short* __restrict__ xh,
                                                       const short* __restrict__ xl,
                                                       const short* __restrict__ Wh,
                                                       const short* __restrict__ Wl,
                                                       short* __restrict__ Qh,
                                                       short* __restrict__ Ql,
                                                       short* __restrict__ Kh,
                                                       short* __restrict__ Kl,
                                                       short* __restrict__ Vw) {
    const int z = blockIdx.z;                       // 0=Q 1=K 2=V
    const short* Wbh = Wh + (size_t)z * DM * DM;
    const short* Wbl = Wl + (size_t)z * DM * DM;
    const int tile_m = blockIdx.x * 64;
    const int tile_n = blockIdx.y * 64;
    const int w = threadIdx.x >> 6, lane = threadIdx.x & 63;
    const int l15 = lane & 15, lg = lane >> 4;
    const int am = tile_m + w * 16 + l15;
    const int ko = lg * 8;

    f32x4 zero4 = {0.f, 0.f, 0.f, 0.f};
    f32x4 acc[4] = {zero4, zero4, zero4, zero4};

    const short* arow_h = xh + (size_t)am * DM + ko;
    const short* arow_l = xl + (size_t)am * DM + ko;
    const short* browh[4];
    const short* browl[4];
#pragma unroll
    for (int nf = 0; nf < 4; ++nf) {
        size_t off = (size_t)(tile_n + nf * 16 + l15) * DM + ko;
        browh[nf] = Wbh + off;
        browl[nf] = Wbl + off;
    }

    for (int kk = 0; kk < DM; kk += 32) {
        bf16x8 ah = ldb(arow_h + kk);
        bf16x8 al = ldb(arow_l + kk);
#pragma unroll
        for (int nf = 0; nf < 4; ++nf) {
            bf16x8 bh = ldb(browh[nf] + kk);
            bf16x8 bl = ldb(browl[nf] + kk);
            acc[nf] = __builtin_amdgcn_mfma_f32_16x16x32_bf16(ah, bh, acc[nf], 0, 0, 0);
            acc[nf] = __builtin_amdgcn_mfma_f32_16x16x32_bf16(al, bh, acc[nf], 0, 0, 0);
            acc[nf] = __builtin_amdgcn_mfma_f32_16x16x32_bf16(ah, bl, acc[nf], 0, 0, 0);
        }
    }

#pragma unroll
    for (int nf = 0; nf < 4; ++nf) {
        int col = tile_n + nf * 16 + l15;
        int h = col >> 6, dh = col & 63;
#pragma unroll
        for (int r = 0; r < 4; ++r) {
            int m = tile_m + w * 16 + lg * 4 + r;
            int b = m >> 11, nt = m & (NT - 1);
            int bh_ = b * NH + h;
            float y = acc[nf][r];
            size_t oidx = ((size_t)bh_ * NT + nt) * HD + dh;
            if (z == 0) {
                unsigned short hi = f2bf(y);
                Qh[oidx] = (short)hi;
                Ql[oidx] = (short)f2bf(y - bf2f(hi));
            } else if (z == 1) {
                unsigned short hi = f2bf(y);
                Kh[oidx] = (short)hi;
                Kl[oidx] = (short)f2bf(y - bf2f(hi));
            } else {
                Vw[((size_t)bh_ * HD + dh) * NT + nt] = (short)f2bf(y);  // transposed
            }
        }
    }
}

// ---------------- fused causal attention ----------------
// grid (N/64, B*H); block 256 = 4 waves, wave w owns q-rows [qb*64+w*16, +16).
// Kh,Kl,V^T tiles (64x64 bf16) staged in LDS with 16B-chunk XOR swizzle
// (chunk ^= row&7) killing the stride-128B bank conflict on ds_read_b128.
// Logits: S = qh*kh + ql*kh + qh*kl (~17-bit mantissa, fp32 accum).

__global__ __launch_bounds__(256) void attn_kernel(const short* __restrict__ Qh,
                                                   const short* __restrict__ Ql,
                                                   const short* __restrict__ Kh,
                                                   const short* __restrict__ Kl,
                                                   const short* __restrict__ Vw,
                                                   float* __restrict__ out) {
    const int qb = blockIdx.x;
    const int bh = blockIdx.y;
    const int tid = threadIdx.x;
    const int w = tid >> 6, lane = tid & 63;
    const int l15 = lane & 15, lg = lane >> 4;

    __shared__ short Ksh[64 * 64];
    __shared__ short Ksl[64 * 64];
    __shared__ short Vs[64 * 64];
    __shared__ short Ps[4][16 * 72];   // per-wave P transpose buffer (padded stride 72)

    const int q0 = qb * 64 + w * 16;
    const size_t qoff = (size_t)bh * NT * HD;
    const short* Khb = Kh + qoff;
    const short* Klb = Kl + qoff;
    const short* Vbase = Vw + (size_t)bh * HD * NT;

    bf16x8 qfh[2], qfl[2];
#pragma unroll
    for (int g = 0; g < 2; ++g) {
        size_t qi = qoff + (size_t)(q0 + l15) * HD + g * 32 + lg * 8;
        qfh[g] = ldb(Qh + qi);
        qfl[g] = ldb(Ql + qi);
    }

    f32x4 zero4 = {0.f, 0.f, 0.f, 0.f};
    f32x4 o[4] = {zero4, zero4, zero4, zero4};
    float m_run[4] = {-1e30f, -1e30f, -1e30f, -1e30f};
    float l_run[4] = {0.f, 0.f, 0.f, 0.f};

    for (int kt = 0; kt <= qb; ++kt) {
        __syncthreads();   // previous iteration's LDS reads complete
        // stage Kh, Kl, V^T tiles: 3 x 512 16B-chunks, swizzled
#pragma unroll
        for (int c = tid; c < 1536; c += 256) {
            int arr = c >> 9, idx = c & 511;
            int row = idx >> 3, ch = idx & 7;
            int swz = (ch ^ (row & 7)) << 3;
            const short* src;
            short* dst;
            if (arr == 0)      { dst = &Ksh[row * 64 + swz]; src = Khb + (size_t)(kt * 64 + row) * HD + ch * 8; }
            else if (arr == 1) { dst = &Ksl[row * 64 + swz]; src = Klb + (size_t)(kt * 64 + row) * HD + ch * 8; }
            else               { dst = &Vs[row * 64 + swz];  src = Vbase + (size_t)row * NT + kt * 64 + ch * 8; }
            *(uint4*)dst = *(const uint4*)src;
        }
        __syncthreads();

        // ---- S = Q K^T (hi/lo) ----
        f32x4 s[4] = {zero4, zero4, zero4, zero4};
#pragma unroll
        for (int nf = 0; nf < 4; ++nf) {
            int kv = nf * 16 + l15;
#pragma unroll
            for (int g = 0; g < 2; ++g) {
                int so = kv * 64 + (((g * 4 + lg) ^ (kv & 7)) << 3);
                bf16x8 kfh = ldb(&Ksh[so]);
                bf16x8 kfl = ldb(&Ksl[so]);
                s[nf] = __builtin_amdgcn_mfma_f32_16x16x32_bf16(qfh[g], kfh, s[nf], 0, 0, 0);
                s[nf] = __builtin_amdgcn_mfma_f32_16x16x32_bf16(qfl[g], kfh, s[nf], 0, 0, 0);
                s[nf] = __builtin_amdgcn_mfma_f32_16x16x32_bf16(qfh[g], kfl, s[nf], 0, 0, 0);
            }
        }

        // ---- causal mask + online softmax (rows live on 16-lane groups) ----
#pragma unroll
        for (int r = 0; r < 4; ++r) {
            int qg = q0 + lg * 4 + r;
            float mx = -1e30f;
#pragma unroll
            for (int nf = 0; nf < 4; ++nf) {
                int kvg = kt * 64 + nf * 16 + l15;
                float sv = s[nf][r];
                if (kvg > qg) sv = -1e30f;
                s[nf][r] = sv;
                mx = fmaxf(mx, sv);
            }
#pragma unroll
            for (int msk = 1; msk < 16; msk <<= 1) mx = fmaxf(mx, __shfl_xor(mx, msk));
            float mn = fmaxf(m_run[r], mx);
            float alpha = __expf(m_run[r] - mn);
            m_run[r] = mn;
            float rs = 0.f;
#pragma unroll
            for (int nf = 0; nf < 4; ++nf) {
                float pv = __expf(s[nf][r] - mn);
                s[nf][r] = pv;
                rs += pv;
            }
#pragma unroll
            for (int msk = 1; msk < 16; msk <<= 1) rs += __shfl_xor(rs, msk);
            l_run[r] = l_run[r] * alpha + rs;
#pragma unroll
            for (int nfd = 0; nfd < 4; ++nfd) o[nfd][r] *= alpha;
        }

        // ---- P through per-wave LDS into A-fragment layout ----
#pragma unroll
        for (int nf = 0; nf < 4; ++nf)
#pragma unroll
            for (int r = 0; r < 4; ++r)
                Ps[w][(lg * 4 + r) * 72 + nf * 16 + l15] = (short)f2bf(s[nf][r]);
        // same-wave write->read through same shared array: compiler inserts lgkmcnt wait
        bf16x8 pf[2];
#pragma unroll
        for (int g = 0; g < 2; ++g)
            pf[g] = ldb(&Ps[w][l15 * 72 + g * 32 + lg * 8]);

        // ---- O += P V ----
#pragma unroll
        for (int nfd = 0; nfd < 4; ++nfd) {
            int d = nfd * 16 + l15;
#pragma unroll
            for (int g = 0; g < 2; ++g) {
                bf16x8 vf = ldb(&Vs[d * 64 + (((g * 4 + lg) ^ (d & 7)) << 3)]);
                o[nfd] = __builtin_amdgcn_mfma_f32_16x16x32_bf16(pf[g], vf, o[nfd], 0, 0, 0);
            }
        }
    }

    // ---- epilogue: out[b, q, h*64+d] = o / l ----
    const int b = bh / NH, h = bh % NH;
#pragma unroll
    for (int r = 0; r < 4; ++r) {
        float inv = 1.0f / l_run[r];
        int qg = q0 + lg * 4 + r;
        float* orow = out + ((size_t)(b * NT + qg)) * DM + h * HD;
#pragma unroll
        for (int nfd = 0; nfd < 4; ++nfd)
            orow[nfd * 16 + l15] = o[nfd][r] * inv;
    }
}

// ---------------- launch ----------------

extern "C" void kernel_launch(void* const* d_in, const int* in_sizes, int n_in,
                              void* d_out, int out_size, void* d_ws, size_t ws_size,
                              hipStream_t stream) {
    const float* x  = (const float*)d_in[0];
    const float* Wq = (const float*)d_in[1];
    const float* Wk = (const float*)d_in[2];
    const float* Wv = (const float*)d_in[3];
    float* outp = (float*)d_out;

    const size_t MD = (size_t)MT * DM;   // 3,145,728
    const size_t DD = (size_t)DM * DM;   //   589,824

    short* wsp = (short*)d_ws;
    short* xh = wsp;            // MD
    short* xl = xh + MD;        // MD
    short* Wh = xl + MD;        // 3*DD
    short* Wl = Wh + 3 * DD;    // 3*DD
    short* Qh = Wl + 3 * DD;    // MD
    short* Ql = Qh + MD;        // MD
    short* Kh = Ql + MD;        // MD
    short* Kl = Kh + MD;        // MD
    short* Vw = Kl + MD;        // MD (transposed: [bh][hd][n])

    int n8x = (int)(MD / 8);
    cvt_x_kernel<<<dim3((n8x + 255) / 256), 256, 0, stream>>>(x, xh, xl, n8x);
    int per8 = (int)(DD / 8);
    cvt_w_kernel<<<dim3((3 * per8 + 255) / 256), 256, 0, stream>>>(Wq, Wk, Wv, Wh, Wl, per8);
    qkv_proj_kernel<<<dim3(MT / 64, DM / 64, 3), 256, 0, stream>>>(xh, xl, Wh, Wl,
                                                                   Qh, Ql, Kh, Kl, Vw);
    attn_kernel<<<dim3(NT / 64, Bsz * NH), 256, 0, stream>>>(Qh, Ql, Kh, Kl, Vw, outp);
}

// Round 4
// 249.447 us; speedup vs baseline: 1.7539x; 1.7539x over previous
//
#include <hip/hip_runtime.h>
#include <hip/hip_bf16.h>
#include <stdint.h>

#define Bsz 2
#define NT  2048
#define DM  768
#define NH  12
#define HD  64
#define MT  (Bsz * NT)   // 4096 tokens total
#define NCAT (3 * DM)    // 2304 concatenated Q,K,V output cols

typedef float  f32x4  __attribute__((ext_vector_type(4)));
typedef short  s16x8  __attribute__((ext_vector_type(8)));
typedef __bf16 bf16x8 __attribute__((ext_vector_type(8)));

#define GLOBAL_AS __attribute__((address_space(1)))
#define SHARED_AS __attribute__((address_space(3)))

__device__ inline unsigned short f2bf(float f) {
    union { float f; uint32_t u; } v; v.f = f;
    uint32_t u = v.u;
    return (unsigned short)((u + 0x7FFFu + ((u >> 16) & 1u)) >> 16);  // RNE
}
__device__ inline float bf2f(unsigned short h) {
    union { uint32_t u; float f; } v; v.u = ((uint32_t)h) << 16;
    return v.f;
}
__device__ inline bf16x8 ldb(const short* p) {
    return __builtin_bit_cast(bf16x8, *(const s16x8*)p);
}

// ---------------- conversion kernels ----------------

__global__ __launch_bounds__(256) void cvt_x_kernel(const float* __restrict__ x,
                                                    short* __restrict__ xh,
                                                    short* __restrict__ xl, int n8) {
    int i = blockIdx.x * blockDim.x + threadIdx.x;
    if (i >= n8) return;
    const float4* p = (const float4*)x + (size_t)i * 2;
    float4 a = p[0], b = p[1];
    float v[8] = {a.x, a.y, a.z, a.w, b.x, b.y, b.z, b.w};
    union { unsigned short s[8]; uint4 q; } H, L;
#pragma unroll
    for (int j = 0; j < 8; ++j) {
        unsigned short h = f2bf(v[j]);
        H.s[j] = h;
        L.s[j] = f2bf(v[j] - bf2f(h));   // residual: x ~= hi + lo to ~17 mantissa bits
    }
    ((uint4*)xh)[i] = H.q;
    ((uint4*)xl)[i] = L.q;
}

__global__ __launch_bounds__(256) void cvt_w_kernel(const float* __restrict__ Wq,
                                                    const float* __restrict__ Wk,
                                                    const float* __restrict__ Wv,
                                                    short* __restrict__ Wh,
                                                    short* __restrict__ Wl, int per8) {
    int i = blockIdx.x * blockDim.x + threadIdx.x;
    if (i >= 3 * per8) return;
    const float* src; int j;
    if (i < per8)          { src = Wq; j = i; }
    else if (i < 2 * per8) { src = Wk; j = i - per8; }
    else                   { src = Wv; j = i - 2 * per8; }
    const float4* p = (const float4*)src + (size_t)j * 2;
    float4 a = p[0], b = p[1];
    float v[8] = {a.x, a.y, a.z, a.w, b.x, b.y, b.z, b.w};
    union { unsigned short s[8]; uint4 q; } H, L;
#pragma unroll
    for (int t = 0; t < 8; ++t) {
        unsigned short h = f2bf(v[t]);
        H.s[t] = h;
        L.s[t] = f2bf(v[t] - bf2f(h));
    }
    ((uint4*)Wh)[i] = H.q;
    ((uint4*)Wl)[i] = L.q;
}

// ---------------- QKV projection: y = x @ Wcat^T (hi/lo x, hi/lo W) ----------------
// 128x128 tile over concatenated [MT][NCAT] output; 4 waves of 64x64; BK=32.
// LDS: 2(dbuf) x 4(Ah,Al,Bh,Bl) x 128x32 bf16 = 64 KB; global_load_lds width=16,
// linear LDS layout (dest must be base + lane*16 — guide §5 caveat).
// y = xh*Wh + xl*Wh + xh*Wl (dropped xl*Wl ~ 2^-18 rel).

#define BM 128
#define BK 32
#define KSTEPS (DM / BK)   // 24

__global__ __launch_bounds__(256, 2) void qkv_proj_kernel(
        const short* __restrict__ xh, const short* __restrict__ xl,
        const short* __restrict__ Wh, const short* __restrict__ Wl,
        short* __restrict__ Qh, short* __restrict__ Ql,
        short* __restrict__ Kh, short* __restrict__ Kl,
        short* __restrict__ Vw) {
    __shared__ short lds[2][4][BM * BK];   // [dbuf][Ah,Al,Bh,Bl][row*32+k]

    const int tid = threadIdx.x;
    const int w = tid >> 6, lane = tid & 63;
    const int l15 = lane & 15, lg = lane >> 4;
    const int wr = w >> 1, wc = w & 1;

    const int tile_m = blockIdx.x * BM;
    const int tile_n = blockIdx.y * BM;    // concatenated col base

    // staging: wave w owns array w (Ah,Al,Bh,Bl); 8 issues of 1KB each (16 rows x 64B)
    const int srow = lane >> 2;            // 0..15
    const int scol = (lane & 3) * 8;       // element offset in row
    const short* gsrc;
    if (w == 0)      gsrc = xh + (size_t)tile_m * DM;
    else if (w == 1) gsrc = xl + (size_t)tile_m * DM;
    else if (w == 2) gsrc = Wh + (size_t)tile_n * DM;   // Wcat[ncat][k] layout
    else             gsrc = Wl + (size_t)tile_n * DM;
    const short* gsrc_lane = gsrc + (size_t)srow * DM + scol;

    f32x4 zero4 = {0.f, 0.f, 0.f, 0.f};
    f32x4 acc[4][4];
#pragma unroll
    for (int i = 0; i < 4; ++i)
#pragma unroll
        for (int j = 0; j < 4; ++j) acc[i][j] = zero4;

    auto stage = [&](int buf, int kt) {
        const short* g = gsrc_lane + kt * BK;
#pragma unroll
        for (int j = 0; j < 8; ++j) {
            __builtin_amdgcn_global_load_lds(
                (const GLOBAL_AS void*)(g + (size_t)j * 16 * DM),
                (SHARED_AS void*)(&lds[buf][w][j * 512]),
                16, 0, 0);
        }
    };

    stage(0, 0);
    int cur = 0;
    for (int kt = 0; kt < KSTEPS; ++kt) {
        __syncthreads();                       // buf[cur] staged; prior reads drained
        if (kt + 1 < KSTEPS) stage(cur ^ 1, kt + 1);   // flies under the MFMAs

        bf16x8 ah[4], al[4], bh[4], bl[4];
#pragma unroll
        for (int f = 0; f < 4; ++f) {
            int arow = wr * 64 + f * 16 + l15;
            ah[f] = ldb(&lds[cur][0][arow * BK + lg * 8]);
            al[f] = ldb(&lds[cur][1][arow * BK + lg * 8]);
            int brow = wc * 64 + f * 16 + l15;
            bh[f] = ldb(&lds[cur][2][brow * BK + lg * 8]);
            bl[f] = ldb(&lds[cur][3][brow * BK + lg * 8]);
        }
#pragma unroll
        for (int mf = 0; mf < 4; ++mf)
#pragma unroll
            for (int nf = 0; nf < 4; ++nf) {
                acc[mf][nf] = __builtin_amdgcn_mfma_f32_16x16x32_bf16(ah[mf], bh[nf], acc[mf][nf], 0, 0, 0);
                acc[mf][nf] = __builtin_amdgcn_mfma_f32_16x16x32_bf16(al[mf], bh[nf], acc[mf][nf], 0, 0, 0);
                acc[mf][nf] = __builtin_amdgcn_mfma_f32_16x16x32_bf16(ah[mf], bl[nf], acc[mf][nf], 0, 0, 0);
            }
        cur ^= 1;
    }

    // ---- epilogue ----
    const int zq = tile_n / DM;            // 0=Q 1=K 2=V (tiles never straddle: 768%128==0)
    const int ncol0 = tile_n % DM;
#pragma unroll
    for (int mf = 0; mf < 4; ++mf) {
#pragma unroll
        for (int nf = 0; nf < 4; ++nf) {
            int col = ncol0 + wc * 64 + nf * 16 + l15;
            int h = col >> 6, dh = col & 63;
            int m0 = tile_m + wr * 64 + mf * 16 + lg * 4;
            int b = m0 >> 11, nt0 = m0 & (NT - 1);
            int bh_ = b * NH + h;
            if (zq == 2) {
                union { short s[4]; short4 v; } pk;
#pragma unroll
                for (int r = 0; r < 4; ++r) pk.s[r] = (short)f2bf(acc[mf][nf][r]);
                *(short4*)&Vw[((size_t)bh_ * HD + dh) * NT + nt0] = pk.v;  // V transposed
            } else {
                short* Hp = (zq == 0) ? Qh : Kh;
                short* Lp = (zq == 0) ? Ql : Kl;
#pragma unroll
                for (int r = 0; r < 4; ++r) {
                    float y = acc[mf][nf][r];
                    unsigned short hi = f2bf(y);
                    size_t oidx = ((size_t)bh_ * NT + nt0 + r) * HD + dh;
                    Hp[oidx] = (short)hi;
                    Lp[oidx] = (short)f2bf(y - bf2f(hi));
                }
            }
        }
    }
}

// ---------------- fused causal attention (unchanged from round 3) ----------------

__global__ __launch_bounds__(256) void attn_kernel(const short* __restrict__ Qh,
                                                   const short* __restrict__ Ql,
                                                   const short* __restrict__ Kh,
                                                   const short* __restrict__ Kl,
                                                   const short* __restrict__ Vw,
                                                   float* __restrict__ out) {
    const int qb = blockIdx.x;
    const int bh = blockIdx.y;
    const int tid = threadIdx.x;
    const int w = tid >> 6, lane = tid & 63;
    const int l15 = lane & 15, lg = lane >> 4;

    __shared__ short Ksh[64 * 64];
    __shared__ short Ksl[64 * 64];
    __shared__ short Vs[64 * 64];
    __shared__ short Ps[4][16 * 72];   // per-wave P transpose buffer (padded stride 72)

    const int q0 = qb * 64 + w * 16;
    const size_t qoff = (size_t)bh * NT * HD;
    const short* Khb = Kh + qoff;
    const short* Klb = Kl + qoff;
    const short* Vbase = Vw + (size_t)bh * HD * NT;

    bf16x8 qfh[2], qfl[2];
#pragma unroll
    for (int g = 0; g < 2; ++g) {
        size_t qi = qoff + (size_t)(q0 + l15) * HD + g * 32 + lg * 8;
        qfh[g] = ldb(Qh + qi);
        qfl[g] = ldb(Ql + qi);
    }

    f32x4 zero4 = {0.f, 0.f, 0.f, 0.f};
    f32x4 o[4] = {zero4, zero4, zero4, zero4};
    float m_run[4] = {-1e30f, -1e30f, -1e30f, -1e30f};
    float l_run[4] = {0.f, 0.f, 0.f, 0.f};

    for (int kt = 0; kt <= qb; ++kt) {
        __syncthreads();   // previous iteration's LDS reads complete
#pragma unroll
        for (int c = tid; c < 1536; c += 256) {
            int arr = c >> 9, idx = c & 511;
            int row = idx >> 3, ch = idx & 7;
            int swz = (ch ^ (row & 7)) << 3;
            const short* src;
            short* dst;
            if (arr == 0)      { dst = &Ksh[row * 64 + swz]; src = Khb + (size_t)(kt * 64 + row) * HD + ch * 8; }
            else if (arr == 1) { dst = &Ksl[row * 64 + swz]; src = Klb + (size_t)(kt * 64 + row) * HD + ch * 8; }
            else               { dst = &Vs[row * 64 + swz];  src = Vbase + (size_t)row * NT + kt * 64 + ch * 8; }
            *(uint4*)dst = *(const uint4*)src;
        }
        __syncthreads();

        // ---- S = Q K^T (hi/lo) ----
        f32x4 s[4] = {zero4, zero4, zero4, zero4};
#pragma unroll
        for (int nf = 0; nf < 4; ++nf) {
            int kv = nf * 16 + l15;
#pragma unroll
            for (int g = 0; g < 2; ++g) {
                int so = kv * 64 + (((g * 4 + lg) ^ (kv & 7)) << 3);
                bf16x8 kfh = ldb(&Ksh[so]);
                bf16x8 kfl = ldb(&Ksl[so]);
                s[nf] = __builtin_amdgcn_mfma_f32_16x16x32_bf16(qfh[g], kfh, s[nf], 0, 0, 0);
                s[nf] = __builtin_amdgcn_mfma_f32_16x16x32_bf16(qfl[g], kfh, s[nf], 0, 0, 0);
                s[nf] = __builtin_amdgcn_mfma_f32_16x16x32_bf16(qfh[g], kfl, s[nf], 0, 0, 0);
            }
        }

        // ---- causal mask + online softmax ----
#pragma unroll
        for (int r = 0; r < 4; ++r) {
            int qg = q0 + lg * 4 + r;
            float mx = -1e30f;
#pragma unroll
            for (int nf = 0; nf < 4; ++nf) {
                int kvg = kt * 64 + nf * 16 + l15;
                float sv = s[nf][r];
                if (kvg > qg) sv = -1e30f;
                s[nf][r] = sv;
                mx = fmaxf(mx, sv);
            }
#pragma unroll
            for (int msk = 1; msk < 16; msk <<= 1) mx = fmaxf(mx, __shfl_xor(mx, msk));
            float mn = fmaxf(m_run[r], mx);
            float alpha = __expf(m_run[r] - mn);
            m_run[r] = mn;
            float rs = 0.f;
#pragma unroll
            for (int nf = 0; nf < 4; ++nf) {
                float pv = __expf(s[nf][r] - mn);
                s[nf][r] = pv;
                rs += pv;
            }
#pragma unroll
            for (int msk = 1; msk < 16; msk <<= 1) rs += __shfl_xor(rs, msk);
            l_run[r] = l_run[r] * alpha + rs;
#pragma unroll
            for (int nfd = 0; nfd < 4; ++nfd) o[nfd][r] *= alpha;
        }

        // ---- P through per-wave LDS into A-fragment layout ----
#pragma unroll
        for (int nf = 0; nf < 4; ++nf)
#pragma unroll
            for (int r = 0; r < 4; ++r)
                Ps[w][(lg * 4 + r) * 72 + nf * 16 + l15] = (short)f2bf(s[nf][r]);
        bf16x8 pf[2];
#pragma unroll
        for (int g = 0; g < 2; ++g)
            pf[g] = ldb(&Ps[w][l15 * 72 + g * 32 + lg * 8]);

        // ---- O += P V ----
#pragma unroll
        for (int nfd = 0; nfd < 4; ++nfd) {
            int d = nfd * 16 + l15;
#pragma unroll
            for (int g = 0; g < 2; ++g) {
                bf16x8 vf = ldb(&Vs[d * 64 + (((g * 4 + lg) ^ (d & 7)) << 3)]);
                o[nfd] = __builtin_amdgcn_mfma_f32_16x16x32_bf16(pf[g], vf, o[nfd], 0, 0, 0);
            }
        }
    }

    // ---- epilogue ----
    const int b = bh / NH, h = bh % NH;
#pragma unroll
    for (int r = 0; r < 4; ++r) {
        float inv = 1.0f / l_run[r];
        int qg = q0 + lg * 4 + r;
        float* orow = out + ((size_t)(b * NT + qg)) * DM + h * HD;
#pragma unroll
        for (int nfd = 0; nfd < 4; ++nfd)
            orow[nfd * 16 + l15] = o[nfd][r] * inv;
    }
}

// ---------------- launch ----------------

extern "C" void kernel_launch(void* const* d_in, const int* in_sizes, int n_in,
                              void* d_out, int out_size, void* d_ws, size_t ws_size,
                              hipStream_t stream) {
    const float* x  = (const float*)d_in[0];
    const float* Wq = (const float*)d_in[1];
    const float* Wk = (const float*)d_in[2];
    const float* Wv = (const float*)d_in[3];
    float* outp = (float*)d_out;

    const size_t MD = (size_t)MT * DM;   // 3,145,728
    const size_t DD = (size_t)DM * DM;   //   589,824

    short* wsp = (short*)d_ws;
    short* xh = wsp;            // MD
    short* xl = xh + MD;        // MD
    short* Wh = xl + MD;        // 3*DD
    short* Wl = Wh + 3 * DD;    // 3*DD
    short* Qh = Wl + 3 * DD;    // MD
    short* Ql = Qh + MD;        // MD
    short* Kh = Ql + MD;        // MD
    short* Kl = Kh + MD;        // MD
    short* Vw = Kl + MD;        // MD (transposed: [bh][hd][n])

    int n8x = (int)(MD / 8);
    cvt_x_kernel<<<dim3((n8x + 255) / 256), 256, 0, stream>>>(x, xh, xl, n8x);
    int per8 = (int)(DD / 8);
    cvt_w_kernel<<<dim3((3 * per8 + 255) / 256), 256, 0, stream>>>(Wq, Wk, Wv, Wh, Wl, per8);
    qkv_proj_kernel<<<dim3(MT / BM, NCAT / BM), 256, 0, stream>>>(xh, xl, Wh, Wl,
                                                                  Qh, Ql, Kh, Kl, Vw);
    attn_kernel<<<dim3(NT / 64, Bsz * NH), 256, 0, stream>>>(Qh, Ql, Kh, Kl, Vw, outp);
}